// Round 1
// baseline (2616.342 us; speedup 1.0000x reference)
//
#include <hip/hip_runtime.h>

#define SEQ 512
#define BATCH 64
#define NN 1024
#define SS 64

// ---- transpose W1,W2 (1024x1024 f32) into workspace: Wt[i*N+j] = W[j*N+i] ----
__global__ void transpose2(const float* __restrict__ A, const float* __restrict__ Bm,
                           float* __restrict__ At, float* __restrict__ Bt) {
    __shared__ float tile[32][33];
    const float* in = blockIdx.z ? Bm : A;
    float* out      = blockIdx.z ? Bt : At;
    int bx = blockIdx.x * 32, by = blockIdx.y * 32;
    int tx = threadIdx.x, ty = threadIdx.y;   // block 32x8
#pragma unroll
    for (int r = 0; r < 32; r += 8)
        tile[ty + r][tx] = in[(by + ty + r) * NN + (bx + tx)];
    __syncthreads();
#pragma unroll
    for (int r = 0; r < 32; r += 8)
        out[(bx + ty + r) * NN + (by + tx)] = tile[tx][ty + r];
}

// ---- main LIF kernel: 1 block per batch element, thread n = neuron n ----
__global__ __launch_bounds__(1024) void lif_kernel(
    const float* __restrict__ W1T, const float* __restrict__ W2T,
    const float* __restrict__ decay1, const float* __restrict__ decay2,
    const float* __restrict__ th1, const float* __restrict__ th2,
    const float* __restrict__ init1, const float* __restrict__ init2,
    const int* __restrict__ inp_ids, const int* __restrict__ inp_num,
    float* __restrict__ out)
{
    const int b = blockIdx.x;
    const int n = threadIdx.x;
    const int lane = n & 63;
    const int wid  = n >> 6;

    __shared__ int lds_ids[SS];
    __shared__ int s_num;
    __shared__ int slotsA[NN];
    __shared__ int slotsB[NN];
    __shared__ int wtotA[16], wtot2A[16];
    __shared__ int wtotB[16], wtot2B[16];

    float v1 = init1[b * NN + n];
    float v2 = init2[b * NN + n];
    const float d1 = decay1[n], d2 = decay2[n];
    const float t1 = th1[n],    t2 = th2[n];
    const float t1b = __fmul_rn(0.9f, t1);
    const float t2b = __fmul_rn(0.9f, t2);
    const float omd1 = __fadd_rn(1.0f, -d1);
    const float omd2 = __fadd_rn(1.0f, -d2);

    // output layout (floats): ids1 | ids2 | cnt1 | cnt2 | st1 | st2
    float* out_ids1 = out;
    float* out_ids2 = out + (size_t)SEQ * BATCH * SS;
    float* out_cnt1 = out + (size_t)2 * SEQ * BATCH * SS;
    float* out_cnt2 = out_cnt1 + (size_t)SEQ * BATCH * 2;
    float* out_st1  = out_cnt2 + (size_t)SEQ * BATCH * 2;
    float* out_st2  = out_st1  + (size_t)SEQ * BATCH * NN;

    const unsigned long long lmask_lt = (1ull << lane) - 1ull;

    for (int t = 0; t < SEQ; ++t) {
        __syncthreads();  // protect LDS reuse from previous iteration
        if (n < SS) lds_ids[n] = inp_ids[((size_t)t * BATCH + b) * SS + n];
        if (n == 0) s_num = inp_num[t * BATCH + b];
        __syncthreads();

        // ---- layer 1 input current: I1 = sum_{s<num} W1T[ids[s]][n] ----
        const int num = s_num;
        float I1 = 0.0f;
        int s = 0;
        for (; s + 4 <= num; s += 4) {
            float a0 = W1T[(size_t)lds_ids[s + 0] * NN + n];
            float a1 = W1T[(size_t)lds_ids[s + 1] * NN + n];
            float a2 = W1T[(size_t)lds_ids[s + 2] * NN + n];
            float a3 = W1T[(size_t)lds_ids[s + 3] * NN + n];
            I1 = __fadd_rn(I1, a0);
            I1 = __fadd_rn(I1, a1);
            I1 = __fadd_rn(I1, a2);
            I1 = __fadd_rn(I1, a3);
        }
        for (; s < num; ++s)
            I1 = __fadd_rn(I1, W1T[(size_t)lds_ids[s] * NN + n]);

        // v1 = d1*v1 + (1-d1)*I1  (no FMA contraction, matches numpy order)
        v1 = __fadd_rn(__fmul_rn(d1, v1), __fmul_rn(omd1, I1));
        const bool spk1  = v1 > t1;
        const bool near1 = v1 > t1b;

        unsigned long long bal1 = __ballot(spk1);
        unsigned long long bal2 = __ballot(near1);
        if (lane == 0) { wtotA[wid] = __popcll(bal1); wtot2A[wid] = __popcll(bal2); }
        __syncthreads();

        int waveoff = 0, totalA = 0, total2A = 0;
#pragma unroll
        for (int w = 0; w < 16; ++w) {
            int tw = wtotA[w];
            if (w < wid) waveoff += tw;
            totalA  += tw;
            total2A += wtot2A[w];
        }
        const int spk_lt1 = waveoff + (int)__popcll(bal1 & lmask_lt);
        const int slot1 = spk1 ? spk_lt1 : (totalA + n - spk_lt1);
        slotsA[slot1] = n;
        __syncthreads();

        if (n < SS) out_ids1[((size_t)t * BATCH + b) * SS + n] = (float)slotsA[n];
        if (n == 0) {
            out_cnt1[((size_t)t * BATCH + b) * 2 + 0] = (float)totalA;
            out_cnt1[((size_t)t * BATCH + b) * 2 + 1] = (float)total2A;
        }
        if (spk1) v1 = 0.0f;
        out_st1[((size_t)t * BATCH + b) * NN + n] = v1;

        // ---- layer 2: I2 = sum over spiking j (ascending) of W2T[j][n] ----
        float I2 = 0.0f;
        int k = 0;
        for (; k + 4 <= totalA; k += 4) {
            float a0 = W2T[(size_t)slotsA[k + 0] * NN + n];
            float a1 = W2T[(size_t)slotsA[k + 1] * NN + n];
            float a2 = W2T[(size_t)slotsA[k + 2] * NN + n];
            float a3 = W2T[(size_t)slotsA[k + 3] * NN + n];
            I2 = __fadd_rn(I2, a0);
            I2 = __fadd_rn(I2, a1);
            I2 = __fadd_rn(I2, a2);
            I2 = __fadd_rn(I2, a3);
        }
        for (; k < totalA; ++k)
            I2 = __fadd_rn(I2, W2T[(size_t)slotsA[k] * NN + n]);

        v2 = __fadd_rn(__fmul_rn(d2, v2), __fmul_rn(omd2, I2));
        const bool spk2  = v2 > t2;
        const bool near2 = v2 > t2b;

        unsigned long long bal3 = __ballot(spk2);
        unsigned long long bal4 = __ballot(near2);
        if (lane == 0) { wtotB[wid] = __popcll(bal3); wtot2B[wid] = __popcll(bal4); }
        __syncthreads();

        int waveoffB = 0, totalB = 0, total2B = 0;
#pragma unroll
        for (int w = 0; w < 16; ++w) {
            int tw = wtotB[w];
            if (w < wid) waveoffB += tw;
            totalB  += tw;
            total2B += wtot2B[w];
        }
        const int spk_lt2 = waveoffB + (int)__popcll(bal3 & lmask_lt);
        const int slot2 = spk2 ? spk_lt2 : (totalB + n - spk_lt2);
        slotsB[slot2] = n;
        __syncthreads();

        if (n < SS) out_ids2[((size_t)t * BATCH + b) * SS + n] = (float)slotsB[n];
        if (n == 0) {
            out_cnt2[((size_t)t * BATCH + b) * 2 + 0] = (float)totalB;
            out_cnt2[((size_t)t * BATCH + b) * 2 + 1] = (float)total2B;
        }
        if (spk2) v2 = 0.0f;
        out_st2[((size_t)t * BATCH + b) * NN + n] = v2;
    }
}

extern "C" void kernel_launch(void* const* d_in, const int* in_sizes, int n_in,
                              void* d_out, int out_size, void* d_ws, size_t ws_size,
                              hipStream_t stream) {
    const float* W1     = (const float*)d_in[0];
    const float* W2     = (const float*)d_in[1];
    const float* decay1 = (const float*)d_in[2];
    const float* decay2 = (const float*)d_in[3];
    const float* th1    = (const float*)d_in[4];
    const float* th2    = (const float*)d_in[5];
    const float* init1  = (const float*)d_in[6];
    const float* init2  = (const float*)d_in[7];
    const int* inp_ids  = (const int*)d_in[8];
    const int* inp_num  = (const int*)d_in[9];
    float* out = (float*)d_out;

    float* W1T = (float*)d_ws;
    float* W2T = W1T + (size_t)NN * NN;

    dim3 tb(32, 8, 1), tg(NN / 32, NN / 32, 2);
    transpose2<<<tg, tb, 0, stream>>>(W1, W2, W1T, W2T);
    lif_kernel<<<BATCH, NN, 0, stream>>>(W1T, W2T, decay1, decay2, th1, th2,
                                         init1, init2, inp_ids, inp_num, out);
}

// Round 2
// 1890.359 us; speedup vs baseline: 1.3840x; 1.3840x over previous
//
#include <hip/hip_runtime.h>

#define SEQ 512
#define BATCH 64
#define NN 1024
#define SS 64

// ---- transpose W1,W2 (1024x1024 f32) into workspace: Wt[i*N+j] = W[j*N+i] ----
__global__ void transpose2(const float* __restrict__ A, const float* __restrict__ Bm,
                           float* __restrict__ At, float* __restrict__ Bt) {
    __shared__ float tile[32][33];
    const float* in = blockIdx.z ? Bm : A;
    float* out      = blockIdx.z ? Bt : At;
    int bx = blockIdx.x * 32, by = blockIdx.y * 32;
    int tx = threadIdx.x, ty = threadIdx.y;   // block 32x8
#pragma unroll
    for (int r = 0; r < 32; r += 8)
        tile[ty + r][tx] = in[(by + ty + r) * NN + (bx + tx)];
    __syncthreads();
#pragma unroll
    for (int r = 0; r < 32; r += 8)
        out[(bx + ty + r) * NN + (by + tx)] = tile[tx][ty + r];
}

// ---- main LIF kernel: 1 block per batch element, thread n = neuron n ----
__global__ __launch_bounds__(1024) void lif_kernel(
    const float* __restrict__ W1T, const float* __restrict__ W2T,
    const float* __restrict__ decay1, const float* __restrict__ decay2,
    const float* __restrict__ th1, const float* __restrict__ th2,
    const float* __restrict__ init1, const float* __restrict__ init2,
    const int* __restrict__ inp_ids, const int* __restrict__ inp_num,
    float* __restrict__ out)
{
    const int b = blockIdx.x;
    const int n = threadIdx.x;
    const int lane = n & 63;
    const int wid  = n >> 6;

    __shared__ int ids_buf[2][SS];
    __shared__ int s_num[2];
    __shared__ int slotsA[NN];
    __shared__ int slotsB[NN];
    __shared__ int wtotA[16], wtot2A[16];
    __shared__ int wtotB[16], wtot2B[16];

    float v1 = init1[b * NN + n];
    float v2 = init2[b * NN + n];
    const float d1 = decay1[n], d2 = decay2[n];
    const float t1 = th1[n],    t2 = th2[n];
    const float t1b = __fmul_rn(0.9f, t1);
    const float t2b = __fmul_rn(0.9f, t2);
    const float omd1 = __fadd_rn(1.0f, -d1);
    const float omd2 = __fadd_rn(1.0f, -d2);

    // output layout (floats): ids1 | ids2 | cnt1 | cnt2 | st1 | st2
    float* out_ids1 = out;
    float* out_ids2 = out + (size_t)SEQ * BATCH * SS;
    float* out_cnt1 = out + (size_t)2 * SEQ * BATCH * SS;
    float* out_cnt2 = out_cnt1 + (size_t)SEQ * BATCH * 2;
    float* out_st1  = out_cnt2 + (size_t)SEQ * BATCH * 2;
    float* out_st2  = out_st1  + (size_t)SEQ * BATCH * NN;

    const unsigned long long lmask_lt = (1ull << lane) - 1ull;

    // preload step-0 ids/num
    if (n < SS) ids_buf[0][n] = __builtin_nontemporal_load(&inp_ids[(size_t)b * SS + n]);
    if (n == 0) s_num[0] = __builtin_nontemporal_load(&inp_num[b]);
    __syncthreads();

    for (int t = 0; t < SEQ; ++t) {
        const int* ids = ids_buf[t & 1];
        const int num  = s_num[t & 1];

        // prefetch next step's ids/num into the other buffer (read after B4 of this step)
        if (t + 1 < SEQ) {
            if (n < SS)
                ids_buf[(t + 1) & 1][n] =
                    __builtin_nontemporal_load(&inp_ids[((size_t)(t + 1) * BATCH + b) * SS + n]);
            if (n == 0)
                s_num[(t + 1) & 1] = __builtin_nontemporal_load(&inp_num[(t + 1) * BATCH + b]);
        }

        // ---- layer 1 input current: I1 = sum_{s<num} W1T[ids[s]][n] ----
        float I1 = 0.0f;
        {
            const int nfull = num >> 4;
            const int rem   = num & 15;
            int sbase = 0;
            for (int r = 0; r < nfull; ++r, sbase += 16) {
                float a[16];
#pragma unroll
                for (int j = 0; j < 16; ++j)
                    a[j] = W1T[(ids[sbase + j] << 10) + n];
#pragma unroll
                for (int j = 0; j < 16; ++j)
                    I1 = __fadd_rn(I1, a[j]);
            }
            if (rem) {
                float a[16];
#pragma unroll
                for (int j = 0; j < 16; ++j)          // ids[] always has 64 valid entries
                    a[j] = W1T[(ids[sbase + j] << 10) + n];
#pragma unroll
                for (int j = 0; j < 16; ++j)
                    if (j < rem) I1 = __fadd_rn(I1, a[j]);
            }
        }

        // v1 = d1*v1 + (1-d1)*I1  (no FMA contraction, matches numpy order)
        v1 = __fadd_rn(__fmul_rn(d1, v1), __fmul_rn(omd1, I1));
        const bool spk1  = v1 > t1;
        const bool near1 = v1 > t1b;

        unsigned long long bal1 = __ballot(spk1);
        unsigned long long bal2 = __ballot(near1);
        if (lane == 0) { wtotA[wid] = __popcll(bal1); wtot2A[wid] = __popcll(bal2); }
        __syncthreads();                                            // B1

        int waveoff = 0, totalA = 0, total2A = 0;
#pragma unroll
        for (int w = 0; w < 16; ++w) {
            int tw = wtotA[w];
            if (w < wid) waveoff += tw;
            totalA  += tw;
            total2A += wtot2A[w];
        }
        const int spk_lt1 = waveoff + (int)__popcll(bal1 & lmask_lt);
        const int slot1 = spk1 ? spk_lt1 : (totalA + n - spk_lt1);
        slotsA[slot1] = n;
        __syncthreads();                                            // B2

        if (n < SS)
            __builtin_nontemporal_store((float)slotsA[n],
                                        &out_ids1[((size_t)t * BATCH + b) * SS + n]);
        if (n == 0) {
            __builtin_nontemporal_store((float)totalA,
                                        &out_cnt1[((size_t)t * BATCH + b) * 2 + 0]);
            __builtin_nontemporal_store((float)total2A,
                                        &out_cnt1[((size_t)t * BATCH + b) * 2 + 1]);
        }
        if (spk1) v1 = 0.0f;
        __builtin_nontemporal_store(v1, &out_st1[((size_t)t * BATCH + b) * NN + n]);

        // ---- layer 2: I2 = sum over spiking j (ascending) of W2T[j][n] ----
        float I2 = 0.0f;
        if (totalA > 0) {
            const int kfull = totalA >> 4;
            const int krem  = totalA & 15;
            int kbase = 0;
            for (int r = 0; r < kfull; ++r, kbase += 16) {
                float a[16];
#pragma unroll
                for (int j = 0; j < 16; ++j)
                    a[j] = W2T[(slotsA[kbase + j] << 10) + n];
#pragma unroll
                for (int j = 0; j < 16; ++j)
                    I2 = __fadd_rn(I2, a[j]);
            }
            if (krem) {
                float a[16];
#pragma unroll
                for (int j = 0; j < 16; ++j)          // slotsA[] is a permutation of 0..1023
                    a[j] = W2T[(slotsA[kbase + j] << 10) + n];
#pragma unroll
                for (int j = 0; j < 16; ++j)
                    if (j < krem) I2 = __fadd_rn(I2, a[j]);
            }
        }

        v2 = __fadd_rn(__fmul_rn(d2, v2), __fmul_rn(omd2, I2));
        const bool spk2  = v2 > t2;
        const bool near2 = v2 > t2b;

        unsigned long long bal3 = __ballot(spk2);
        unsigned long long bal4 = __ballot(near2);
        if (lane == 0) { wtotB[wid] = __popcll(bal3); wtot2B[wid] = __popcll(bal4); }
        __syncthreads();                                            // B3

        int waveoffB = 0, totalB = 0, total2B = 0;
#pragma unroll
        for (int w = 0; w < 16; ++w) {
            int tw = wtotB[w];
            if (w < wid) waveoffB += tw;
            totalB  += tw;
            total2B += wtot2B[w];
        }
        const int spk_lt2 = waveoffB + (int)__popcll(bal3 & lmask_lt);
        const int slot2 = spk2 ? spk_lt2 : (totalB + n - spk_lt2);
        slotsB[slot2] = n;
        __syncthreads();                                            // B4

        if (n < SS)
            __builtin_nontemporal_store((float)slotsB[n],
                                        &out_ids2[((size_t)t * BATCH + b) * SS + n]);
        if (n == 0) {
            __builtin_nontemporal_store((float)totalB,
                                        &out_cnt2[((size_t)t * BATCH + b) * 2 + 0]);
            __builtin_nontemporal_store((float)total2B,
                                        &out_cnt2[((size_t)t * BATCH + b) * 2 + 1]);
        }
        if (spk2) v2 = 0.0f;
        __builtin_nontemporal_store(v2, &out_st2[((size_t)t * BATCH + b) * NN + n]);
    }
}

extern "C" void kernel_launch(void* const* d_in, const int* in_sizes, int n_in,
                              void* d_out, int out_size, void* d_ws, size_t ws_size,
                              hipStream_t stream) {
    const float* W1     = (const float*)d_in[0];
    const float* W2     = (const float*)d_in[1];
    const float* decay1 = (const float*)d_in[2];
    const float* decay2 = (const float*)d_in[3];
    const float* th1    = (const float*)d_in[4];
    const float* th2    = (const float*)d_in[5];
    const float* init1  = (const float*)d_in[6];
    const float* init2  = (const float*)d_in[7];
    const int* inp_ids  = (const int*)d_in[8];
    const int* inp_num  = (const int*)d_in[9];
    float* out = (float*)d_out;

    float* W1T = (float*)d_ws;
    float* W2T = W1T + (size_t)NN * NN;

    dim3 tb(32, 8, 1), tg(NN / 32, NN / 32, 2);
    transpose2<<<tg, tb, 0, stream>>>(W1, W2, W1T, W2T);
    lif_kernel<<<BATCH, NN, 0, stream>>>(W1T, W2T, decay1, decay2, th1, th2,
                                         init1, init2, inp_ids, inp_num, out);
}